// Round 6
// baseline (113.843 us; speedup 1.0000x reference)
//
#include <hip/hip_runtime.h>
#include <math.h>

#define NPTS 10000
#define XPT 10             // x-points per thread: 6 packed (DP pipe) + 4 scalar (SP)
#define KP 6
#define KS 4
#define AXCH 4             // 4 * 256 * 10 = 10240 >= 10000
#define MAXTILE 400        // max slice length (float4 per y) = 6.4 KB LDS

typedef float float2v __attribute__((ext_vector_type(2)));

// d = a*b + c (packed 2xf32 on the FP64 pipe; per-half IEEE fma, bit-equal to
// scalar fmaf chains of the same order).
#define PKFMA(d, a, b, c) \
    asm("v_pk_fma_f32 %0, %1, %2, %3" : "=v"(d) : "v"(a), "v"(b), "v"(c))

// Fixed-point encode of partial max m (range [-16,16), granularity 2^-11),
// rounded DOWN. Clamp-high is safe: any slice clamping high is a candidate.
__device__ __forceinline__ unsigned short enc_q(float m) {
    int q = (int)floorf((m + 16.0f) * 2048.0f);
    q = q < 0 ? 0 : (q > 65535 ? 65535 : q);
    return (unsigned short)q;
}

// ---------------------------------------------------------------------------
// Pass A: per (combo, slice, x-chunk) partial max of m_j = dot(x,y_j)-0.5|y_j|^2
// (equiv. min d2). Pair-packed LDS broadcast (2 ds_read_b128 per 2 j feed 20
// lane-pairs); 6 x's on v_pk_fma_f32 (DP pipe) + 4 on scalar fmaf (SP pipe).
// Stores u16 fixed-point maxima -> ns=50 fits the 4 MB-ish workspace.
// ---------------------------------------------------------------------------
__global__ __launch_bounds__(256, 4) void knn_max(
    const float* __restrict__ pred_pts, const float* __restrict__ targ_pts,
    unsigned short* __restrict__ wsQ, int nslices)
{
    const int slice = NPTS / nslices;          // 200/250/400: all even
    const int c   = blockIdx.z;
    const int dir = c >> 1, b = c & 1;
    const float* xp = (dir == 0 ? targ_pts : pred_pts) + (size_t)b * NPTS * 3;
    const float* yp = (dir == 0 ? pred_pts : targ_pts) + (size_t)b * NPTS * 3;
    const int s = blockIdx.y;
    const int base = blockIdx.x * (256 * XPT) + threadIdx.x;

    __shared__ float4 spk[MAXTILE];            // 2 float4 per j-pair

    float2v xb[KP][3];
    float   xs[KS][3];
#pragma unroll
    for (int k = 0; k < XPT; ++k) {
        const int n = base + k * 256;
        const int nn = (n < NPTS) ? n : (NPTS - 1);   // clamp; discard on store
        const float v0 = xp[nn * 3 + 0];
        const float v1 = xp[nn * 3 + 1];
        const float v2 = xp[nn * 3 + 2];
        if (k < KP) {
            xb[k][0] = (float2v){v0, v0};
            xb[k][1] = (float2v){v1, v1};
            xb[k][2] = (float2v){v2, v2};
        } else {
            xs[k - KP][0] = v0; xs[k - KP][1] = v1; xs[k - KP][2] = v2;
        }
    }
    float best[XPT];
#pragma unroll
    for (int k = 0; k < XPT; ++k) best[k] = -1e30f;

    const int js = s * slice;
    const int np = slice >> 1;
    for (int p = threadIdx.x; p < np; p += 256) {
        const int j = js + 2 * p;
        const float a0 = yp[j * 3 + 0], b0 = yp[j * 3 + 1], c0 = yp[j * 3 + 2];
        const float a1 = yp[j * 3 + 3], b1 = yp[j * 3 + 4], c1 = yp[j * 3 + 5];
        spk[2 * p]     = make_float4(a0, a1, b0, b1);
        spk[2 * p + 1] = make_float4(c0, c1,
                                     -0.5f * (a0 * a0 + b0 * b0 + c0 * c0),
                                     -0.5f * (a1 * a1 + b1 * b1 + c1 * c1));
    }
    __syncthreads();

#pragma unroll 2
    for (int p = 0; p < np; ++p) {
        const float4 A = spk[2 * p];           // {x0,x1,y0,y1} broadcast
        const float4 B = spk[2 * p + 1];       // {z0,z1,h0,h1}
        const float2v px = {A.x, A.y}, py = {A.z, A.w};
        const float2v pz = {B.x, B.y}, pw = {B.z, B.w};
#pragma unroll
        for (int k = 0; k < KP; ++k) {         // DP pipe
            float2v t;
            PKFMA(t, xb[k][2], pz, pw);
            PKFMA(t, xb[k][1], py, t);
            PKFMA(t, xb[k][0], px, t);
            best[k] = fmaxf(fmaxf(best[k], t.x), t.y);   // v_max3
        }
#pragma unroll
        for (int k = 0; k < KS; ++k) {         // SP pipe
            const float ma = fmaf(xs[k][0], A.x,
                             fmaf(xs[k][1], A.z, fmaf(xs[k][2], B.x, B.z)));
            const float mb = fmaf(xs[k][0], A.y,
                             fmaf(xs[k][1], A.w, fmaf(xs[k][2], B.y, B.w)));
            best[KP + k] = fmaxf(fmaxf(best[KP + k], ma), mb);
        }
    }
#pragma unroll
    for (int k = 0; k < XPT; ++k) {
        const int n = base + k * 256;
        if (n < NPTS)
            wsQ[((size_t)(c * nslices + s)) * NPTS + n] = enc_q(best[k]);
    }
}

// ---------------------------------------------------------------------------
// Pass B: one 64-lane WAVE per x-point (8 waves / 512-thread block).
//   1) read u16 slice maxima (lane s), wave-max via shfl butterfly
//   2) for every candidate slice (q >= qmax-8: provably contains the true
//      winner), lane-parallel exact rescan; ascending s + strict > keeps the
//      first-occurrence argmax (jnp.argmin tie semantics)
//   3) lane 0: Welsch term + normal-cosine term; block-reduce to float2.
// ---------------------------------------------------------------------------
__global__ __launch_bounds__(512) void finalize(
    const float* __restrict__ pred_pts, const float* __restrict__ pred_nrm,
    const float* __restrict__ targ_pts, const float* __restrict__ targ_nrm,
    const unsigned short* __restrict__ wsQ, float2* __restrict__ wsB,
    int nslices)
{
    const int c   = blockIdx.y;
    const int dir = c >> 1, b = c & 1;
    const float* xp = (dir == 0 ? targ_pts : pred_pts) + (size_t)b * NPTS * 3;
    const float* xn = (dir == 0 ? targ_nrm : pred_nrm) + (size_t)b * NPTS * 3;
    const float* yp = (dir == 0 ? pred_pts : targ_pts) + (size_t)b * NPTS * 3;
    const float* yn = (dir == 0 ? pred_nrm : targ_nrm) + (size_t)b * NPTS * 3;

    const int lane = threadIdx.x & 63;
    const int wv   = threadIdx.x >> 6;
    const int n    = blockIdx.x * 8 + wv;

    float t0 = 0.f, t1 = 0.f;
    if (n < NPTS) {
        const int slice = NPTS / nslices;
        int q = -1;
        if (lane < nslices)
            q = wsQ[((size_t)(c * nslices + lane)) * NPTS + n];
        int qmax = q;
#pragma unroll
        for (int w = 1; w < 64; w <<= 1)
            qmax = max(qmax, __shfl_xor(qmax, w));

        const float a  = xp[n * 3 + 0];
        const float bb = xp[n * 3 + 1];
        const float cc = xp[n * 3 + 2];

        float rb = -1e30f;
        int bidx = 1 << 30;
        for (int s = 0; s < nslices; ++s) {
            const int qs = __shfl(q, s);
            if (qs >= qmax - 8) {              // candidate slice: exact rescan
                const int jend = (s + 1) * slice;
                for (int j = s * slice + lane; j < jend; j += 64) {
                    const float ya = yp[j * 3 + 0];
                    const float yb = yp[j * 3 + 1];
                    const float yc = yp[j * 3 + 2];
                    const float hy = -0.5f * (ya * ya + yb * yb + yc * yc);
                    const float m  = fmaf(a, ya, fmaf(bb, yb, fmaf(cc, yc, hy)));
                    if (m > rb) { rb = m; bidx = j; }   // in-lane: j ascending
                }
            }
        }
#pragma unroll
        for (int w = 1; w < 64; w <<= 1) {
            const float mo = __shfl_xor(rb, w);
            const int   jo = __shfl_xor(bidx, w);
            if (mo > rb || (mo == rb && jo < bidx)) { rb = mo; bidx = jo; }
        }
        if (lane == 0) {
            const float hx = -0.5f * (a * a + bb * bb + cc * cc);
            float d2 = -2.0f * (rb + hx);
            d2 = fmaxf(d2, 0.0f);
            const float w = __expf(-(d2 * d2) * (1.0f / 0.18f));  // 2*ALPHA^2
            t0 = w * d2;
            const float nx0 = xn[n * 3 + 0], nx1 = xn[n * 3 + 1], nx2 = xn[n * 3 + 2];
            const float ny0 = yn[(size_t)bidx * 3 + 0];
            const float ny1 = yn[(size_t)bidx * 3 + 1];
            const float ny2 = yn[(size_t)bidx * 3 + 2];
            const float nnx = fmaxf(sqrtf(nx0 * nx0 + nx1 * nx1 + nx2 * nx2), 1e-6f);
            const float nny = fmaxf(sqrtf(ny0 * ny0 + ny1 * ny1 + ny2 * ny2), 1e-6f);
            const float cosv = (nx0 * ny0 + nx1 * ny1 + nx2 * ny2) / (nnx * nny);
            t1 = 1.0f - fabsf(cosv);
        }
    }

    __shared__ float r0[512], r1[512];
    r0[threadIdx.x] = t0;
    r1[threadIdx.x] = t1;
    __syncthreads();
    for (int st = 256; st > 0; st >>= 1) {
        if (threadIdx.x < st) {
            r0[threadIdx.x] += r0[threadIdx.x + st];
            r1[threadIdx.x] += r1[threadIdx.x + st];
        }
        __syncthreads();
    }
    if (threadIdx.x == 0)
        wsB[blockIdx.y * gridDim.x + blockIdx.x] = make_float2(r0[0], r1[0]);
}

// ---------------------------------------------------------------------------
// Final deterministic reduction of the block partials.
// ---------------------------------------------------------------------------
__global__ __launch_bounds__(256) void reduce_final(
    const float2* __restrict__ wsB, int nblocks, float* __restrict__ out)
{
    __shared__ float r0[256], r1[256];
    const int t = threadIdx.x;
    float s0 = 0.f, s1 = 0.f;
    for (int i = t; i < nblocks; i += 256) {
        const float2 v = wsB[i];
        s0 += v.x;
        s1 += v.y;
    }
    r0[t] = s0; r1[t] = s1;
    __syncthreads();
    for (int st = 128; st > 0; st >>= 1) {
        if (t < st) { r0[t] += r0[t + st]; r1[t] += r1[t + st]; }
        __syncthreads();
    }
    if (t == 0) {
        out[0] = 0.5f * r0[0];                 // mean over B=2 of per-batch sums
        out[1] = r1[0] * (1.0f / 20000.0f);    // mean over B*N, both dirs
    }
}

extern "C" void kernel_launch(void* const* d_in, const int* in_sizes, int n_in,
                              void* d_out, int out_size, void* d_ws, size_t ws_size,
                              hipStream_t stream)
{
    const float* pred_pts = (const float*)d_in[0];
    const float* pred_nrm = (const float*)d_in[1];
    const float* targ_pts = (const float*)d_in[2];
    const float* targ_nrm = (const float*)d_in[3];
    float* out = (float*)d_out;

    const int BXCH = (NPTS + 7) / 8;     // 1250 blocks per combo in pass B
    const size_t WSB_B = (size_t)4 * BXCH * sizeof(float2);

    // Largest slice count whose u16 workspace fits; slices all even, <= MAXTILE.
    const int ladder[3] = {50, 40, 25};
    int ns = 25;
    for (int i = 0; i < 3; ++i) {
        const size_t need = (size_t)4 * ladder[i] * NPTS * sizeof(unsigned short)
                          + WSB_B + 256;
        if (need <= ws_size) { ns = ladder[i]; break; }
    }

    unsigned short* wsQ = (unsigned short*)d_ws;        // 4*ns*NPTS u16
    float2* wsB = (float2*)((char*)d_ws + (size_t)4 * ns * NPTS * sizeof(unsigned short));

    dim3 gA(AXCH, ns, 4);
    knn_max<<<gA, 256, 0, stream>>>(pred_pts, targ_pts, wsQ, ns);

    dim3 gB(BXCH, 4);
    finalize<<<gB, 512, 0, stream>>>(pred_pts, pred_nrm, targ_pts, targ_nrm,
                                     wsQ, wsB, ns);

    reduce_final<<<1, 256, 0, stream>>>(wsB, BXCH * 4, out);
}

// Round 7
// 51.993 us; speedup vs baseline: 2.1896x; 2.1896x over previous
//
#include <hip/hip_runtime.h>
#include <math.h>

#define NPTS 10000
#define XPT 10             // x-points per thread: 6 packed (DP pipe) + 4 scalar (SP)
#define KP 6
#define KS 4
#define AXCH 4             // 4 * 256 * 10 = 10240 >= 10000
#define NS 125             // slices; slice = 80 (even)
#define SLICE 80

typedef float float2v __attribute__((ext_vector_type(2)));

// d = a*b + c (packed 2xf32 on the FP64 pipe; per-half IEEE fma, bit-equal to
// scalar fmaf chains of the same order).
#define PKFMA(d, a, b, c) \
    asm("v_pk_fma_f32 %0, %1, %2, %3" : "=v"(d) : "v"(a), "v"(b), "v"(c))

// Order-preserving bijection f32 -> u32 (monotone: a<b <=> ord(a)<ord(b)).
__device__ __forceinline__ unsigned int ord32(float f) {
    unsigned int b = __float_as_uint(f);
    return (b & 0x80000000u) ? ~b : (b | 0x80000000u);
}

// ---------------------------------------------------------------------------
// Pass A: per (combo, slice, x-chunk) max of m_j = dot(x,y_j)-0.5|y_j|^2 over
// the slice (equiv. min d2). Pair-packed LDS broadcast; 6 x's on v_pk_fma_f32
// (DP pipe) + 4 on scalar fmaf (SP pipe). Publishes per-x global winner via
// u64 atomicMax of (ord(m)<<32 | ~slice): exact max, ties -> smaller slice.
// ns=125 -> 2000 blocks -> ~31 waves/CU: latency fully hidden (fix for R4/R6).
// ---------------------------------------------------------------------------
__global__ __launch_bounds__(256, 4) void knn_max(
    const float* __restrict__ pred_pts, const float* __restrict__ targ_pts,
    unsigned long long* __restrict__ gmax)
{
    const int c   = blockIdx.z;
    const int dir = c >> 1, b = c & 1;
    const float* xp = (dir == 0 ? targ_pts : pred_pts) + (size_t)b * NPTS * 3;
    const float* yp = (dir == 0 ? pred_pts : targ_pts) + (size_t)b * NPTS * 3;
    const int s = blockIdx.y;
    const int base = blockIdx.x * (256 * XPT) + threadIdx.x;

    __shared__ float4 spk[SLICE];              // 2 float4 per j-pair (1.28 KB)

    float2v xb[KP][3];
    float   xs[KS][3];
#pragma unroll
    for (int k = 0; k < XPT; ++k) {
        const int n = base + k * 256;
        const int nn = (n < NPTS) ? n : (NPTS - 1);   // clamp; discard on store
        const float v0 = xp[nn * 3 + 0];
        const float v1 = xp[nn * 3 + 1];
        const float v2 = xp[nn * 3 + 2];
        if (k < KP) {
            xb[k][0] = (float2v){v0, v0};
            xb[k][1] = (float2v){v1, v1};
            xb[k][2] = (float2v){v2, v2};
        } else {
            xs[k - KP][0] = v0; xs[k - KP][1] = v1; xs[k - KP][2] = v2;
        }
    }
    float best[XPT];
#pragma unroll
    for (int k = 0; k < XPT; ++k) best[k] = -1e30f;

    const int js = s * SLICE;
    const int np = SLICE >> 1;                 // 40 j-pairs
    for (int p = threadIdx.x; p < np; p += 256) {
        const int j = js + 2 * p;
        const float a0 = yp[j * 3 + 0], b0 = yp[j * 3 + 1], c0 = yp[j * 3 + 2];
        const float a1 = yp[j * 3 + 3], b1 = yp[j * 3 + 4], c1 = yp[j * 3 + 5];
        // hy chain written with explicit fmaf so finalize can reproduce it.
        const float h0 = -0.5f * fmaf(c0, c0, fmaf(b0, b0, a0 * a0));
        const float h1 = -0.5f * fmaf(c1, c1, fmaf(b1, b1, a1 * a1));
        spk[2 * p]     = make_float4(a0, a1, b0, b1);
        spk[2 * p + 1] = make_float4(c0, c1, h0, h1);
    }
    __syncthreads();

#pragma unroll 2
    for (int p = 0; p < np; ++p) {
        const float4 A = spk[2 * p];           // {x0,x1,y0,y1} broadcast
        const float4 B = spk[2 * p + 1];       // {z0,z1,h0,h1}
        const float2v px = {A.x, A.y}, py = {A.z, A.w};
        const float2v pz = {B.x, B.y}, pw = {B.z, B.w};
#pragma unroll
        for (int k = 0; k < KP; ++k) {         // DP pipe
            float2v t;
            PKFMA(t, xb[k][2], pz, pw);        // x2*z + hy
            PKFMA(t, xb[k][1], py, t);
            PKFMA(t, xb[k][0], px, t);
            best[k] = fmaxf(fmaxf(best[k], t.x), t.y);   // v_max3
        }
#pragma unroll
        for (int k = 0; k < KS; ++k) {         // SP pipe (same chain order)
            const float ma = fmaf(xs[k][0], A.x,
                             fmaf(xs[k][1], A.z, fmaf(xs[k][2], B.x, B.z)));
            const float mb = fmaf(xs[k][0], A.y,
                             fmaf(xs[k][1], A.w, fmaf(xs[k][2], B.y, B.w)));
            best[KP + k] = fmaxf(fmaxf(best[KP + k], ma), mb);
        }
    }

    const unsigned int slo = ~(unsigned int)s;   // ties -> smaller slice wins
#pragma unroll
    for (int k = 0; k < XPT; ++k) {
        const int n = base + k * 256;
        if (n < NPTS) {
            const unsigned long long key =
                ((unsigned long long)ord32(best[k]) << 32) | slo;
            atomicMax(&gmax[(size_t)c * NPTS + n], key);
        }
    }
}

// ---------------------------------------------------------------------------
// Pass B: 8-lane group per x-point. Decode winning slice from gmax (exact),
// lane-parallel rescan of that slice only (10 iters; identical fmaf chain ->
// same m values; strict > with ascending j + tie->smaller j = exact
// first-occurrence argmax), then Welsch + normal terms; block-reduce.
// ---------------------------------------------------------------------------
__global__ __launch_bounds__(256) void finalize(
    const float* __restrict__ pred_pts, const float* __restrict__ pred_nrm,
    const float* __restrict__ targ_pts, const float* __restrict__ targ_nrm,
    const unsigned long long* __restrict__ gmax, float2* __restrict__ wsB)
{
    const int c   = blockIdx.y;
    const int dir = c >> 1, b = c & 1;
    const float* xp = (dir == 0 ? targ_pts : pred_pts) + (size_t)b * NPTS * 3;
    const float* xn = (dir == 0 ? targ_nrm : pred_nrm) + (size_t)b * NPTS * 3;
    const float* yp = (dir == 0 ? pred_pts : targ_pts) + (size_t)b * NPTS * 3;
    const float* yn = (dir == 0 ? pred_nrm : targ_nrm) + (size_t)b * NPTS * 3;

    const int lane = threadIdx.x & 7;
    const int n = blockIdx.x * 32 + (threadIdx.x >> 3);

    float t0 = 0.f, t1 = 0.f;
    if (n < NPTS) {
        const unsigned long long key = gmax[(size_t)c * NPTS + n];
        const int bs = (int)(~(unsigned int)(key & 0xffffffffu));  // slice
        const float a  = xp[n * 3 + 0];
        const float bb = xp[n * 3 + 1];
        const float cc = xp[n * 3 + 2];
        const int j0 = bs * SLICE;
        float rb = -1e30f;
        int bidx = 1 << 30;
        for (int j = j0 + lane; j < j0 + SLICE; j += 8) {
            const float ya = yp[j * 3 + 0];
            const float yb = yp[j * 3 + 1];
            const float yc = yp[j * 3 + 2];
            const float hy = -0.5f * fmaf(yc, yc, fmaf(yb, yb, ya * ya));
            const float m  = fmaf(a, ya, fmaf(bb, yb, fmaf(cc, yc, hy)));
            if (m > rb) { rb = m; bidx = j; }   // in-lane: j ascending
        }
#pragma unroll
        for (int w = 1; w < 8; w <<= 1) {
            const float mo = __shfl_xor(rb, w);
            const int   jo = __shfl_xor(bidx, w);
            if (mo > rb || (mo == rb && jo < bidx)) { rb = mo; bidx = jo; }
        }
        if (lane == 0) {
            const float hx = -0.5f * fmaf(cc, cc, fmaf(bb, bb, a * a));
            float d2 = -2.0f * (rb + hx);
            d2 = fmaxf(d2, 0.0f);
            const float w = __expf(-(d2 * d2) * (1.0f / 0.18f));  // 2*ALPHA^2
            t0 = w * d2;
            const float nx0 = xn[n * 3 + 0], nx1 = xn[n * 3 + 1], nx2 = xn[n * 3 + 2];
            const float ny0 = yn[(size_t)bidx * 3 + 0];
            const float ny1 = yn[(size_t)bidx * 3 + 1];
            const float ny2 = yn[(size_t)bidx * 3 + 2];
            const float nnx = fmaxf(sqrtf(nx0 * nx0 + nx1 * nx1 + nx2 * nx2), 1e-6f);
            const float nny = fmaxf(sqrtf(ny0 * ny0 + ny1 * ny1 + ny2 * ny2), 1e-6f);
            const float cosv = (nx0 * ny0 + nx1 * ny1 + nx2 * ny2) / (nnx * nny);
            t1 = 1.0f - fabsf(cosv);
        }
    }

    __shared__ float r0[256], r1[256];
    r0[threadIdx.x] = t0;
    r1[threadIdx.x] = t1;
    __syncthreads();
    for (int st = 128; st > 0; st >>= 1) {
        if (threadIdx.x < st) {
            r0[threadIdx.x] += r0[threadIdx.x + st];
            r1[threadIdx.x] += r1[threadIdx.x + st];
        }
        __syncthreads();
    }
    if (threadIdx.x == 0)
        wsB[blockIdx.y * gridDim.x + blockIdx.x] = make_float2(r0[0], r1[0]);
}

// ---------------------------------------------------------------------------
// Final deterministic reduction of the block partials.
// ---------------------------------------------------------------------------
__global__ __launch_bounds__(256) void reduce_final(
    const float2* __restrict__ wsB, int nblocks, float* __restrict__ out)
{
    __shared__ float r0[256], r1[256];
    const int t = threadIdx.x;
    float s0 = 0.f, s1 = 0.f;
    for (int i = t; i < nblocks; i += 256) {
        const float2 v = wsB[i];
        s0 += v.x;
        s1 += v.y;
    }
    r0[t] = s0; r1[t] = s1;
    __syncthreads();
    for (int st = 128; st > 0; st >>= 1) {
        if (t < st) { r0[t] += r0[t + st]; r1[t] += r1[t + st]; }
        __syncthreads();
    }
    if (t == 0) {
        out[0] = 0.5f * r0[0];                 // mean over B=2 of per-batch sums
        out[1] = r1[0] * (1.0f / 20000.0f);    // mean over B*N, both dirs
    }
}

extern "C" void kernel_launch(void* const* d_in, const int* in_sizes, int n_in,
                              void* d_out, int out_size, void* d_ws, size_t ws_size,
                              hipStream_t stream)
{
    const float* pred_pts = (const float*)d_in[0];
    const float* pred_nrm = (const float*)d_in[1];
    const float* targ_pts = (const float*)d_in[2];
    const float* targ_nrm = (const float*)d_in[3];
    float* out = (float*)d_out;

    const int BXCH = (NPTS + 31) / 32;   // 313 blocks per combo in pass B

    unsigned long long* gmax = (unsigned long long*)d_ws;   // 4*NPTS u64 = 320 KB
    float2* wsB = (float2*)((char*)d_ws + (size_t)4 * NPTS * sizeof(unsigned long long));

    // gmax must be 0 every call (keys are always > 0); async memset is
    // graph-capture-safe.
    hipMemsetAsync(gmax, 0, (size_t)4 * NPTS * sizeof(unsigned long long), stream);

    dim3 gA(AXCH, NS, 4);
    knn_max<<<gA, 256, 0, stream>>>(pred_pts, targ_pts, gmax);

    dim3 gB(BXCH, 4);
    finalize<<<gB, 256, 0, stream>>>(pred_pts, pred_nrm, targ_pts, targ_nrm,
                                     gmax, wsB);

    reduce_final<<<1, 256, 0, stream>>>(wsB, BXCH * 4, out);
}